// Round 14
// baseline (578.734 us; speedup 1.0000x reference)
//
#include <hip/hip_runtime.h>
#include <stdint.h>

// LSTM forward, MI355X. H=128, I=270, C=3, B=1024, T=270, NU=512, W rows 398.
// Round-14: scan spread over 256 CUs — 256 blocks x 4 batch rows, 1 gate-element
// per thread. MFMA C-frags redistributed via pre_lds (4 masked ds_write_b128 +
// 1 ds_read_b128), NOT shuffles (r7's mistake). xpc relaid [t][b][unit][gate]
// so xg is one coalesced 8B load/thread. Gates: 7 trans on 1 element (was 4).
// Logits: one wave alternating by t-parity, 4 MFMA vs Wy; softmax on lq=0 lanes.

typedef __attribute__((ext_vector_type(8))) short short8;
typedef __attribute__((ext_vector_type(4))) float f32x4;
typedef __attribute__((ext_vector_type(2))) float f32x2;
typedef __attribute__((ext_vector_type(4))) unsigned int uint4v;
typedef __attribute__((ext_vector_type(2))) unsigned int u32x2;
typedef unsigned short ush;

__device__ __forceinline__ ush f2bf(float f) {
    unsigned u = __float_as_uint(f);
    return (ush)((u + 0x7FFFu + ((u >> 16) & 1u)) >> 16);
}
// Raw barrier: LDS visibility only; vmem ops stay outstanding (T4).
__device__ __forceinline__ void lds_barrier() {
    asm volatile("s_waitcnt lgkmcnt(0)" ::: "memory");
    __builtin_amdgcn_s_barrier();
    __builtin_amdgcn_sched_barrier(0);
    asm volatile("" ::: "memory");
}

// ---------------- pack_w ----------------
__global__ __launch_bounds__(256) void pack_w(
    const float* __restrict__ Wf, const float* __restrict__ Wi,
    const float* __restrict__ Wc, const float* __restrict__ Wo,
    const float* __restrict__ bf_, const float* __restrict__ bi_,
    const float* __restrict__ bc_, const float* __restrict__ bo_,
    ush* __restrict__ Wxp, ush* __restrict__ Whp, float* __restrict__ bpk)
{
    int idx = blockIdx.x * 256 + threadIdx.x;
    if (idx < 512 * 288) {
        int u = idx / 288, i = idx - u * 288;
        int g = u >> 7, j = u & 127;
        const float* Wg = (g == 0) ? Wf : (g == 1) ? Wi : (g == 2) ? Wc : Wo;
        float v = (i < 270) ? Wg[(size_t)j * 398 + 128 + i] : 0.f;
        Wxp[idx] = f2bf(v);
    }
    if (idx < 512 * 128) {
        int u = idx >> 7, k = idx & 127;
        int g = u >> 7, j = u & 127;
        const float* Wg = (g == 0) ? Wf : (g == 1) ? Wi : (g == 2) ? Wc : Wo;
        Whp[idx] = f2bf(Wg[(size_t)j * 398 + k]);
    }
    if (idx < 512) {
        int g = idx >> 7, j = idx & 127;
        const float* bg = (g == 0) ? bf_ : (g == 1) ? bi_ : (g == 2) ? bc_ : bo_;
        bpk[idx] = bg[j];
    }
}

// ---------------- xp_gemm: x read once; xpc layout [r][unit][gate] bf16 ----------------
__global__ __launch_bounds__(256, 2) void xp_gemm(
    const float* __restrict__ x, const ush* __restrict__ Wxp,
    const float* __restrict__ bpk, ush* __restrict__ xpc, int t0)
{
    __shared__ ush A_lds[64 * 296];                 // stride 296 elem -> 2-way banks
    const int tid = threadIdx.x;
    const int l = tid & 63, w = tid >> 6;           // wave w <-> gate w
    const int l16 = l & 15, lq = l >> 4;
    const size_t row0 = (size_t)blockIdx.x * 64;

    // ---- issue all A loads (fp32) ----
    const int srow = tid >> 2, sgrp = tid & 3;      // row 0..63, 8-col group 0..3
    const int r = (int)row0 + srow;
    const int b = r & 1023, tt = (r >> 10) + t0;
    const float* xrow = x + ((size_t)b * 270 + tt) * 270;
    f32x2 stg[9][4];
    #pragma unroll
    for (int ks = 0; ks < 9; ++ks) {
        const int col = ks * 32 + sgrp * 8;
        const float* p = xrow + col;
        if (col + 8 <= 270) {
            stg[ks][0] = *(const f32x2*)p;       stg[ks][1] = *(const f32x2*)(p + 2);
            stg[ks][2] = *(const f32x2*)(p + 4); stg[ks][3] = *(const f32x2*)(p + 6);
        } else {
            float tv[8];
            #pragma unroll
            for (int j = 0; j < 8; ++j) tv[j] = (col + j < 270) ? p[j] : 0.f;
            stg[ks][0] = (f32x2){tv[0], tv[1]}; stg[ks][1] = (f32x2){tv[2], tv[3]};
            stg[ks][2] = (f32x2){tv[4], tv[5]}; stg[ks][3] = (f32x2){tv[6], tv[7]};
        }
    }

    // ---- B-frag base + prefetch ks=0 set; bias ----
    const ush* bptr = Wxp + ((size_t)(w * 128 + l16)) * 288 + lq * 8;
    short8 bA[8], bB[8];
    #pragma unroll
    for (int nt = 0; nt < 8; ++nt) bA[nt] = *(const short8*)(bptr + nt * 4608);
    float bias_v[8];
    #pragma unroll
    for (int nt = 0; nt < 8; ++nt) bias_v[nt] = bpk[w * 128 + nt * 16 + l16];

    // ---- convert + LDS write, one barrier ----
    {
        ush* wrow = &A_lds[srow * 296 + sgrp * 8];
        #pragma unroll
        for (int ks = 0; ks < 9; ++ks) {
            uint4v o;
            #pragma unroll
            for (int p2 = 0; p2 < 4; ++p2) {
                unsigned v;
                asm("v_cvt_pk_bf16_f32 %0, %1, %2"
                    : "=v"(v) : "v"(stg[ks][p2].x), "v"(stg[ks][p2].y));
                o[p2] = v;
            }
            *(uint4v*)(wrow + ks * 32) = o;
        }
    }
    lds_barrier();                                  // bA loads stay in flight

    f32x4 acc[4][8];
    #pragma unroll
    for (int mt = 0; mt < 4; ++mt)
        #pragma unroll
        for (int nt = 0; nt < 8; ++nt)
            acc[mt][nt] = (f32x4){bias_v[nt], bias_v[nt], bias_v[nt], bias_v[nt]};

    // ---- barrier-free K-loop ----
    #pragma unroll
    for (int ks = 0; ks < 9; ++ks) {
        short8* cur = (ks & 1) ? bB : bA;
        short8* nxt = (ks & 1) ? bA : bB;
        if (ks + 1 < 9) {
            const ush* np = bptr + (ks + 1) * 32;
            #pragma unroll
            for (int nt = 0; nt < 8; ++nt) nxt[nt] = *(const short8*)(np + nt * 4608);
        }
        short8 afr[4];
        #pragma unroll
        for (int mt = 0; mt < 4; ++mt)
            afr[mt] = *(const short8*)(&A_lds[(mt * 16 + l16) * 296 + ks * 32 + lq * 8]);
        #pragma unroll
        for (int mt = 0; mt < 4; ++mt)
            #pragma unroll
            for (int nt = 0; nt < 8; ++nt)
                acc[mt][nt] = __builtin_amdgcn_mfma_f32_16x16x32_bf16(
                    afr[mt], cur[nt], acc[mt][nt], 0, 0, 0);
    }

    // ---- store: [r][unit(0..127)][gate] bf16 (L2 merges the 4 gate phases) ----
    #pragma unroll
    for (int mt = 0; mt < 4; ++mt)
        #pragma unroll
        for (int nt = 0; nt < 8; ++nt) {
            int uu = nt * 16 + l16;                 // unit within gate; gate = w
            #pragma unroll
            for (int q = 0; q < 4; ++q) {
                size_t rg = row0 + mt * 16 + lq * 4 + q;
                xpc[(rg * 128 + uu) * 4 + w] = f2bf(acc[mt][nt][q]);
            }
        }
}

// ---------------- lstm_scan: 256 blocks x 4 rows, 1 element/thread ----------------
#define STEPB(T, PS)                                                            \
  {                                                                             \
    const int t_ = (T);                                                         \
    const bool lw_ = (t_ > t0) && (w == 4 * (t_ & 1));                          \
    short8 afr[4];                                                              \
    _Pragma("unroll") for (int kf = 0; kf < 4; ++kf) {                          \
      int off_ = ((l16 * 128 + kf * 32 + lq * 8) * 2) ^ ((l16 & 7) << 4);       \
      afr[kf] = *(const short8*)(hbase + cur * 4096 + off_);                    \
    }                                                                           \
    f32x4 a0_[4], a1_[4];                                                       \
    _Pragma("unroll") for (int g = 0; g < 4; ++g) {                             \
      a0_[g] = (f32x4){0.f, 0.f, 0.f, 0.f};                                     \
      a1_[g] = (f32x4){0.f, 0.f, 0.f, 0.f};                                     \
    }                                                                           \
    _Pragma("unroll") for (int g = 0; g < 4; ++g) {                             \
      a0_[g] = __builtin_amdgcn_mfma_f32_16x16x32_bf16(afr[0], whf[g][0], a0_[g], 0, 0, 0); \
      a1_[g] = __builtin_amdgcn_mfma_f32_16x16x32_bf16(afr[2], whf[g][2], a1_[g], 0, 0, 0); \
      a0_[g] = __builtin_amdgcn_mfma_f32_16x16x32_bf16(afr[1], whf[g][1], a0_[g], 0, 0, 0); \
      a1_[g] = __builtin_amdgcn_mfma_f32_16x16x32_bf16(afr[3], whf[g][3], a1_[g], 0, 0, 0); \
    }                                                                           \
    f32x4 ay0_ = (f32x4){0.f, 0.f, 0.f, 0.f};                                   \
    f32x4 ay1_ = (f32x4){0.f, 0.f, 0.f, 0.f};                                   \
    if (lw_) {                /* logits for t_-1 (afr = h_{t_-1}) */            \
      ay0_ = __builtin_amdgcn_mfma_f32_16x16x32_bf16(afr[0], wyf[0], ay0_, 0, 0, 0); \
      ay1_ = __builtin_amdgcn_mfma_f32_16x16x32_bf16(afr[2], wyf[2], ay1_, 0, 0, 0); \
      ay0_ = __builtin_amdgcn_mfma_f32_16x16x32_bf16(afr[1], wyf[1], ay0_, 0, 0, 0); \
      ay1_ = __builtin_amdgcn_mfma_f32_16x16x32_bf16(afr[3], wyf[3], ay1_, 0, 0, 0); \
    }                                                                           \
    if (lq == 0) {            /* redistribute: rows 0..3 live in regs 0..3 */   \
      _Pragma("unroll") for (int q = 0; q < 4; ++q) {                           \
        f32x4 pv;                                                               \
        pv.x = a0_[0][q] + a1_[0][q];                                           \
        pv.y = a0_[1][q] + a1_[1][q];                                           \
        pv.z = a0_[2][q] + a1_[2][q];                                           \
        pv.w = a0_[3][q] + a1_[3][q];                                           \
        *(f32x4*)(&pre_lds[q][w * 16 + l16][0]) = pv;                           \
      }                                                                         \
    }                                                                           \
    lds_barrier();                                                              \
    f32x4 pr_ = *(const f32x4*)(&pre_lds[row][unit][0]);                        \
    u32x2 pv_ = PS;                                                             \
    float xgf_ = __uint_as_float(pv_.x << 16);                                  \
    float xgi_ = __uint_as_float(pv_.x & 0xffff0000u);                          \
    float xgc_ = __uint_as_float(pv_.y << 16);                                  \
    float xgo_ = __uint_as_float(pv_.y & 0xffff0000u);                          \
    if (t_ + 2 < t1) PS = *(const u32x2*)(xq + (size_t)(t_ + 2 - t0) * TSTEP);  \
    {                                                                           \
      float pf_ = fminf(fmaxf(pr_.x + xgf_, -20.f), 20.f);                      \
      float pi_ = fminf(fmaxf(pr_.y + xgi_, -20.f), 20.f);                      \
      float pc_ = fminf(fmaxf(pr_.z + xgc_, -10.f), 10.f);                      \
      float po_ = fminf(fmaxf(pr_.w + xgo_, -20.f), 20.f);                      \
      float df_ = 1.f + __expf(-pf_);                                           \
      float di_ = 1.f + __expf(-pi_);                                           \
      float ec2_ = __expf(-2.f * pc_);                                          \
      float dc_ = 1.f + ec2_;                                                   \
      float do2_ = 1.f + __expf(-po_);                                          \
      float didc_ = di_ * dc_;                                                  \
      float num_ = c1 * didc_ + (1.f - ec2_) * df_;                             \
      float cn_ = num_ * __builtin_amdgcn_rcpf(df_ * didc_);                    \
      c1 = cn_;                                                                 \
      float cnc_ = fminf(fmaxf(cn_, -10.f), 10.f);                              \
      float et2_ = __expf(-2.f * cnc_);                                         \
      float hv_ = (1.f - et2_) * __builtin_amdgcn_rcpf(do2_ * (1.f + et2_));    \
      int off_ = ((row * 128 + unit) * 2) ^ ((row & 7) << 4);                   \
      *(ush*)(hbase + (cur ^ 1) * 4096 + off_) = f2bf(hv_);                     \
      out0[(size_t)(b0 + row) * (270 * 128) + (size_t)t_ * 128 + unit] = hv_;   \
    }                                                                           \
    lds_barrier();                                                              \
    if (lw_ && lq == 0) {     /* softmax for t_-1: rows=regs, class=l16 */      \
      f32x4 ay_ = ay0_ + ay1_;                                                  \
      _Pragma("unroll") for (int q = 0; q < 4; ++q) {                           \
        float L_ = ay_[q] + byl;                                                \
        if (l16 >= 3) L_ = -1e30f;                                              \
        float m_ = fmaxf(L_, __shfl_xor(L_, 1));                                \
        m_ = fmaxf(m_, __shfl_xor(m_, 2));                                      \
        float e_ = (l16 < 3) ? __expf(L_ - m_) : 0.f;                           \
        float s_ = e_ + __shfl_xor(e_, 1);                                      \
        s_ = s_ + __shfl_xor(s_, 2);                                            \
        if (l16 < 3)                                                            \
          out1[((size_t)(b0 + q) * 270 + (t_ - 1)) * 3 + l16] = e_ * __builtin_amdgcn_rcpf(s_); \
      }                                                                         \
    }                                                                           \
    cur ^= 1;                                                                   \
  }

__global__ __launch_bounds__(512) void lstm_scan(
    const ush* __restrict__ xpc, const ush* __restrict__ Whp,
    float* __restrict__ c_state, float* __restrict__ out0, float* __restrict__ out1,
    const float* __restrict__ Wy, const float* __restrict__ by, int t0, int t1)
{
    __shared__ ush h_lds[2][16 * 128];          // 8 KB, rows 4-15 stay zero
    __shared__ float pre_lds[4][128][4];        // 8 KB redistribute buffer
    const int tid = threadIdx.x;
    const int l = tid & 63, w = tid >> 6;
    const int l16 = l & 15, lq = l >> 4;
    const int b0 = blockIdx.x * 4;
    const int row = tid >> 7;                   // 0..3
    const int unit = tid & 127;
    const int jcol = w * 16 + l16;              // MFMA unit column per wave
    char* hbase = (char*)&h_lds[0][0];

    short8 whf[4][4];
    #pragma unroll
    for (int g = 0; g < 4; ++g) {
        const ush* bw = Whp + ((size_t)(g * 128 + jcol)) * 128 + lq * 8;
        #pragma unroll
        for (int kf = 0; kf < 4; ++kf) whf[g][kf] = *(const short8*)(bw + kf * 32);
    }
    short8 wyf[4];
    #pragma unroll
    for (int kf = 0; kf < 4; ++kf) {
        short8 fr;
        #pragma unroll
        for (int j = 0; j < 8; ++j)
            fr[j] = (l16 < 3) ? (short)f2bf(Wy[l16 * 128 + kf * 32 + lq * 8 + j]) : (short)0;
        wyf[kf] = fr;
    }
    const float byl = (l16 < 3) ? by[l16] : 0.f;

    {   // zero both h buffers (h_0 = 0; rows 4-15 permanent zero padding)
        ush* hp = &h_lds[0][0];
        for (int idx = tid; idx < 2 * 16 * 128; idx += 512) hp[idx] = 0;
    }
    __syncthreads();

    int cur = 0;
    float c1 = 0.f;
    if (t0 != 0) {
        c1 = c_state[(size_t)(b0 + row) * 128 + unit];
        float hvv = out0[(size_t)(b0 + row) * (270 * 128) + (size_t)(t0 - 1) * 128 + unit];
        int off = ((row * 128 + unit) * 2) ^ ((row & 7) << 4);
        *(ush*)(hbase + off) = f2bf(hvv);
        __syncthreads();
    }

    const size_t TSTEP = (size_t)1024 * 128 * 4;    // ush per timestep
    const ush* xq = xpc + ((size_t)(b0 + row) * 128 + unit) * 4;
    u32x2 Pa = *(const u32x2*)(xq);
    u32x2 Pb = *(const u32x2*)(xq + TSTEP);

    for (int t = t0; t < t1; t += 2) {    // chunk lengths are even
        STEPB(t, Pa)
        STEPB(t + 1, Pb)
    }

    // epilogue: logits/softmax for the last h (t1-1), afr = h_lds[cur]
    if (w == 0) {
        short8 afr[4];
        #pragma unroll
        for (int kf = 0; kf < 4; ++kf) {
            int off = ((l16 * 128 + kf * 32 + lq * 8) * 2) ^ ((l16 & 7) << 4);
            afr[kf] = *(const short8*)(hbase + cur * 4096 + off);
        }
        f32x4 ay = (f32x4){0.f, 0.f, 0.f, 0.f};
        ay = __builtin_amdgcn_mfma_f32_16x16x32_bf16(afr[0], wyf[0], ay, 0, 0, 0);
        ay = __builtin_amdgcn_mfma_f32_16x16x32_bf16(afr[1], wyf[1], ay, 0, 0, 0);
        ay = __builtin_amdgcn_mfma_f32_16x16x32_bf16(afr[2], wyf[2], ay, 0, 0, 0);
        ay = __builtin_amdgcn_mfma_f32_16x16x32_bf16(afr[3], wyf[3], ay, 0, 0, 0);
        if (lq == 0) {
            #pragma unroll
            for (int q = 0; q < 4; ++q) {
                float L = ay[q] + byl;
                if (l16 >= 3) L = -1e30f;
                float m = fmaxf(L, __shfl_xor(L, 1));
                m = fmaxf(m, __shfl_xor(m, 2));
                float e = (l16 < 3) ? __expf(L - m) : 0.f;
                float s = e + __shfl_xor(e, 1);
                s = s + __shfl_xor(s, 2);
                if (l16 < 3)
                    out1[((size_t)(b0 + q) * 270 + (t1 - 1)) * 3 + l16] =
                        e * __builtin_amdgcn_rcpf(s);
            }
        }
    }

    if (t1 != 270)
        c_state[(size_t)(b0 + row) * 128 + unit] = c1;
}

// ---------------- host ----------------
extern "C" void kernel_launch(void* const* d_in, const int* in_sizes, int n_in,
                              void* d_out, int out_size, void* d_ws, size_t ws_size,
                              hipStream_t stream) {
    (void)in_sizes; (void)n_in; (void)out_size;
    const float* x   = (const float*)d_in[0];
    const float* Wf  = (const float*)d_in[1];
    const float* Wi  = (const float*)d_in[2];
    const float* Wc  = (const float*)d_in[3];
    const float* Wo  = (const float*)d_in[4];
    const float* Wy  = (const float*)d_in[5];
    const float* bfp = (const float*)d_in[6];
    const float* bip = (const float*)d_in[7];
    const float* bcp = (const float*)d_in[8];
    const float* bop = (const float*)d_in[9];
    const float* byp = (const float*)d_in[10];

    float* out0 = (float*)d_out;                       // [B,T,H]
    float* out1 = out0 + (size_t)1024 * 270 * 128;     // [B,T,3]

    long tc = 6;
    {
        const long cand[6] = {270, 90, 54, 30, 18, 6};
        for (int i = 0; i < 6; ++i) {
            size_t need = (size_t)cand[i] * 1048576u + (2u << 20);
            if (need <= ws_size) { tc = cand[i]; break; }
        }
    }
    char* wsb = (char*)d_ws;
    ush* xpc = (ush*)wsb;                              // tc MB
    char* fx = wsb + (size_t)tc * 1048576u;
    float* c_state = (float*)fx;                       // 512 KB
    ush* Wxp = (ush*)(fx + 524288);                    // 288 KB
    ush* Whp = (ush*)(fx + 524288 + 294912);           // 128 KB
    float* bpk = (float*)(fx + 524288 + 294912 + 131072);

    pack_w<<<576, 256, 0, stream>>>(Wf, Wi, Wc, Wo, bfp, bip, bcp, bop, Wxp, Whp, bpk);

    for (int t0 = 0; t0 < 270; t0 += (int)tc) {
        int Tcur = (270 - t0) < (int)tc ? (270 - t0) : (int)tc;
        int rows = Tcur * 1024;
        xp_gemm<<<rows / 64, 256, 0, stream>>>(x, Wxp, bpk, xpc, t0);
        lstm_scan<<<256, 512, 0, stream>>>(xpc, Whp, c_state, out0, out1, Wy, byp,
                                           t0, t0 + Tcur);
    }
}

// Round 15
// 474.448 us; speedup vs baseline: 1.2198x; 1.2198x over previous
//
#include <hip/hip_runtime.h>
#include <stdint.h>

// LSTM forward, MI355X. H=128, I=270, C=3, B=1024, T=270, NU=512, W rows 398.
// Round-15: r13 base (64 scan blocks x 16 rows — r14's 256-block split regressed
// on MFMA duplication + 3 barriers/step). VALU diet on the scan step:
//   - LDS offsets (afr x4, h-write x4) hoisted to registers; cur is a
//     compile-time 0/1 (loop is unroll-2) so +4096 folds into ds immediates
//   - out0 via 4 persistent pointers bumped +128/step (no 64-bit rebuilds)
//   - xpc prefetch via bumped pointer (no per-step mul)
//   - split-K2 removed (4 indep depth-4 MFMA chains pipeline the same);
//     acc C-init comes straight from the xg unpack; logits = single ay chain.

typedef __attribute__((ext_vector_type(8))) short short8;
typedef __attribute__((ext_vector_type(4))) float f32x4;
typedef __attribute__((ext_vector_type(2))) float f32x2;
typedef __attribute__((ext_vector_type(4))) unsigned int uint4v;
typedef __attribute__((ext_vector_type(2))) unsigned int u32x2;
typedef unsigned short ush;

__device__ __forceinline__ ush f2bf(float f) {
    unsigned u = __float_as_uint(f);
    return (ush)((u + 0x7FFFu + ((u >> 16) & 1u)) >> 16);
}
// Raw barrier: LDS visibility only; vmem ops stay outstanding (T4).
__device__ __forceinline__ void lds_barrier() {
    asm volatile("s_waitcnt lgkmcnt(0)" ::: "memory");
    __builtin_amdgcn_s_barrier();
    __builtin_amdgcn_sched_barrier(0);
    asm volatile("" ::: "memory");
}

// ---------------- pack_w ----------------
__global__ __launch_bounds__(256) void pack_w(
    const float* __restrict__ Wf, const float* __restrict__ Wi,
    const float* __restrict__ Wc, const float* __restrict__ Wo,
    const float* __restrict__ bf_, const float* __restrict__ bi_,
    const float* __restrict__ bc_, const float* __restrict__ bo_,
    ush* __restrict__ Wxp, ush* __restrict__ Whp, float* __restrict__ bpk)
{
    int idx = blockIdx.x * 256 + threadIdx.x;
    if (idx < 512 * 288) {
        int u = idx / 288, i = idx - u * 288;
        int g = u >> 7, j = u & 127;
        const float* Wg = (g == 0) ? Wf : (g == 1) ? Wi : (g == 2) ? Wc : Wo;
        float v = (i < 270) ? Wg[(size_t)j * 398 + 128 + i] : 0.f;
        Wxp[idx] = f2bf(v);
    }
    if (idx < 512 * 128) {
        int u = idx >> 7, k = idx & 127;
        int g = u >> 7, j = u & 127;
        const float* Wg = (g == 0) ? Wf : (g == 1) ? Wi : (g == 2) ? Wc : Wo;
        Whp[idx] = f2bf(Wg[(size_t)j * 398 + k]);
    }
    if (idx < 512) {
        int g = idx >> 7, j = idx & 127;
        const float* bg = (g == 0) ? bf_ : (g == 1) ? bi_ : (g == 2) ? bc_ : bo_;
        bpk[idx] = bg[j];
    }
}

// ---------------- xp_gemm: x read once; xpc layout [t][b/16][512u][16b] ----------------
__global__ __launch_bounds__(256, 2) void xp_gemm(
    const float* __restrict__ x, const ush* __restrict__ Wxp,
    const float* __restrict__ bpk, ush* __restrict__ xpc, int t0)
{
    __shared__ ush A_lds[64 * 296];                 // stride 296 elem -> 2-way banks
    const int tid = threadIdx.x;
    const int l = tid & 63, w = tid >> 6;
    const int l16 = l & 15, lq = l >> 4;
    const size_t row0 = (size_t)blockIdx.x * 64;

    // ---- issue all A loads (fp32) ----
    const int srow = tid >> 2, sgrp = tid & 3;      // row 0..63, 8-col group 0..3
    const int r = (int)row0 + srow;
    const int b = r & 1023, tt = (r >> 10) + t0;
    const float* xrow = x + ((size_t)b * 270 + tt) * 270;
    f32x2 stg[9][4];
    #pragma unroll
    for (int ks = 0; ks < 9; ++ks) {
        const int col = ks * 32 + sgrp * 8;
        const float* p = xrow + col;
        if (col + 8 <= 270) {
            stg[ks][0] = *(const f32x2*)p;       stg[ks][1] = *(const f32x2*)(p + 2);
            stg[ks][2] = *(const f32x2*)(p + 4); stg[ks][3] = *(const f32x2*)(p + 6);
        } else {
            float tv[8];
            #pragma unroll
            for (int j = 0; j < 8; ++j) tv[j] = (col + j < 270) ? p[j] : 0.f;
            stg[ks][0] = (f32x2){tv[0], tv[1]}; stg[ks][1] = (f32x2){tv[2], tv[3]};
            stg[ks][2] = (f32x2){tv[4], tv[5]}; stg[ks][3] = (f32x2){tv[6], tv[7]};
        }
    }

    // ---- B-frag base + prefetch ks=0 set; bias ----
    const ush* bptr = Wxp + ((size_t)(w * 128 + l16)) * 288 + lq * 8;
    short8 bA[8], bB[8];
    #pragma unroll
    for (int nt = 0; nt < 8; ++nt) bA[nt] = *(const short8*)(bptr + nt * 4608);
    float bias_v[8];
    #pragma unroll
    for (int nt = 0; nt < 8; ++nt) bias_v[nt] = bpk[w * 128 + nt * 16 + l16];

    // ---- convert + LDS write, one barrier ----
    {
        ush* wrow = &A_lds[srow * 296 + sgrp * 8];
        #pragma unroll
        for (int ks = 0; ks < 9; ++ks) {
            uint4v o;
            #pragma unroll
            for (int p2 = 0; p2 < 4; ++p2) {
                unsigned v;
                asm("v_cvt_pk_bf16_f32 %0, %1, %2"
                    : "=v"(v) : "v"(stg[ks][p2].x), "v"(stg[ks][p2].y));
                o[p2] = v;
            }
            *(uint4v*)(wrow + ks * 32) = o;
        }
    }
    lds_barrier();                                  // bA loads stay in flight

    f32x4 acc[4][8];
    #pragma unroll
    for (int mt = 0; mt < 4; ++mt)
        #pragma unroll
        for (int nt = 0; nt < 8; ++nt)
            acc[mt][nt] = (f32x4){bias_v[nt], bias_v[nt], bias_v[nt], bias_v[nt]};

    // ---- barrier-free K-loop ----
    #pragma unroll
    for (int ks = 0; ks < 9; ++ks) {
        short8* cur = (ks & 1) ? bB : bA;
        short8* nxt = (ks & 1) ? bA : bB;
        if (ks + 1 < 9) {
            const ush* np = bptr + (ks + 1) * 32;
            #pragma unroll
            for (int nt = 0; nt < 8; ++nt) nxt[nt] = *(const short8*)(np + nt * 4608);
        }
        short8 afr[4];
        #pragma unroll
        for (int mt = 0; mt < 4; ++mt)
            afr[mt] = *(const short8*)(&A_lds[(mt * 16 + l16) * 296 + ks * 32 + lq * 8]);
        #pragma unroll
        for (int mt = 0; mt < 4; ++mt)
            #pragma unroll
            for (int nt = 0; nt < 8; ++nt)
                acc[mt][nt] = __builtin_amdgcn_mfma_f32_16x16x32_bf16(
                    afr[mt], cur[nt], acc[mt][nt], 0, 0, 0);
    }

    // ---- store: [t][b/16][512u][16b], proven f2bf scalar path ----
    const int tloc = (int)(row0 >> 10);
    const int bg0 = ((int)row0 & 1023) >> 4;
    #pragma unroll
    for (int mt = 0; mt < 4; ++mt)
        #pragma unroll
        for (int nt = 0; nt < 8; ++nt) {
            int u = w * 128 + nt * 16 + l16;
            ush* dst = xpc + ((size_t)(tloc * 64 + bg0 + mt) * 512 + u) * 16 + lq * 4;
            #pragma unroll
            for (int q = 0; q < 4; ++q) dst[q] = f2bf(acc[mt][nt][q]);
        }
}

// ---------------- lstm_scan: 16 rows/block, hoisted addressing ----------------
// CUR is a compile-time 0/1 (t-loop is unroll-2); all LDS offsets precomputed.
#define STEPB(T, PS, XP, CUR)                                                   \
  {                                                                             \
    const int t_ = (T);                                                         \
    const bool lw_ = (((w >> 2) ^ (t_ & 1)) == 0) && (t_ > t0);                 \
    short8 afr[4];                                                              \
    _Pragma("unroll") for (int kf = 0; kf < 4; ++kf)                            \
      afr[kf] = *(const short8*)(hbase + (CUR) * 4096 + oaf[kf]);               \
    f32x4 acc_[4];                                                              \
    _Pragma("unroll") for (int g = 0; g < 4; ++g) {                             \
      u32x2 pv_ = PS[g];                                                        \
      acc_[g][0] = __uint_as_float(pv_.x << 16);                                \
      acc_[g][1] = __uint_as_float(pv_.x & 0xffff0000u);                        \
      acc_[g][2] = __uint_as_float(pv_.y << 16);                                \
      acc_[g][3] = __uint_as_float(pv_.y & 0xffff0000u);                        \
    }                                                                           \
    if (t_ + 2 < t1) {                                                          \
      _Pragma("unroll") for (int g = 0; g < 4; ++g)                             \
        PS[g] = *(const u32x2*)((XP) + go[g]);                                  \
    }                                                                           \
    (XP) += 2 * TSTEP;                                                          \
    _Pragma("unroll") for (int kf = 0; kf < 4; ++kf)                            \
      _Pragma("unroll") for (int g = 0; g < 4; ++g)                             \
        acc_[g] = __builtin_amdgcn_mfma_f32_16x16x32_bf16(                      \
            afr[kf], whf[g][kf], acc_[g], 0, 0, 0);                             \
    f32x4 ay_ = (f32x4){0.f, 0.f, 0.f, 0.f};                                    \
    if (lw_) {                /* logits for t_-1 (afr = h_{t_-1}) */            \
      ay_ = __builtin_amdgcn_mfma_f32_16x16x32_bf16(afr[0], wyf[0], ay_, 0, 0, 0); \
      ay_ = __builtin_amdgcn_mfma_f32_16x16x32_bf16(afr[1], wyf[1], ay_, 0, 0, 0); \
      ay_ = __builtin_amdgcn_mfma_f32_16x16x32_bf16(afr[2], wyf[2], ay_, 0, 0, 0); \
      ay_ = __builtin_amdgcn_mfma_f32_16x16x32_bf16(afr[3], wyf[3], ay_, 0, 0, 0); \
    }                                                                           \
    _Pragma("unroll") for (int q = 0; q < 4; ++q) {                             \
      float pf_ = fminf(fmaxf(acc_[0][q], -20.f), 20.f);                        \
      float pi_ = fminf(fmaxf(acc_[1][q], -20.f), 20.f);                        \
      float pc_ = fminf(fmaxf(acc_[2][q], -10.f), 10.f);                        \
      float po_ = fminf(fmaxf(acc_[3][q], -20.f), 20.f);                        \
      float df_ = 1.f + __expf(-pf_);                                           \
      float di_ = 1.f + __expf(-pi_);                                           \
      float ec2_ = __expf(-2.f * pc_);                                          \
      float dc_ = 1.f + ec2_;                                                   \
      float do2_ = 1.f + __expf(-po_);                                          \
      float didc_ = di_ * dc_;                                                  \
      float num_ = c[q] * didc_ + (1.f - ec2_) * df_;                           \
      float cn_ = num_ * __builtin_amdgcn_rcpf(df_ * didc_);                    \
      c[q] = cn_;                                                               \
      float cnc_ = fminf(fmaxf(cn_, -10.f), 10.f);                              \
      float et2_ = __expf(-2.f * cnc_);                                         \
      float hv_ = (1.f - et2_) * __builtin_amdgcn_rcpf(do2_ * (1.f + et2_));    \
      *(ush*)(hbase + ((CUR) ^ 1) * 4096 + ohw[q]) = f2bf(hv_);                 \
      *op[q] = hv_;                                                             \
      op[q] += 128;                                                             \
    }                                                                           \
    lds_barrier();                                                              \
    /* softmax finish AFTER the barrier: overlaps next step's ds_read+MFMA */   \
    if (lw_) {                                                                  \
      int ww_ = w & 3;                                                          \
      float L_ = ((ww_ == 0) ? ay_[0] : (ww_ == 1) ? ay_[1] : (ww_ == 2) ? ay_[2] : ay_[3]) + byl; \
      if (l16 >= 3) L_ = -1e30f;                                                \
      float m_ = fmaxf(L_, __shfl_xor(L_, 1));                                  \
      m_ = fmaxf(m_, __shfl_xor(m_, 2));                                        \
      float e_ = (l16 < 3) ? __expf(L_ - m_) : 0.f;                             \
      float s_ = e_ + __shfl_xor(e_, 1);                                        \
      s_ = s_ + __shfl_xor(s_, 2);                                              \
      if (l16 < 3)                                                              \
        out1[((size_t)(b0 + lq * 4 + ww_) * 270 + (t_ - 1)) * 3 + l16] = e_ * __builtin_amdgcn_rcpf(s_); \
    }                                                                           \
  }

__global__ __launch_bounds__(512) void lstm_scan(
    const ush* __restrict__ xpc, const ush* __restrict__ Whp,
    float* __restrict__ c_state, float* __restrict__ out0, float* __restrict__ out1,
    const float* __restrict__ Wy, const float* __restrict__ by, int t0, int t1)
{
    __shared__ ush h_lds[2][16 * 128];
    const int tid = threadIdx.x;
    const int l = tid & 63, w = tid >> 6;
    const int l16 = l & 15, lq = l >> 4;
    const int b0 = blockIdx.x * 16;
    const int jcol = w * 16 + l16;
    char* hbase = (char*)&h_lds[0][0];

    short8 whf[4][4];
    #pragma unroll
    for (int g = 0; g < 4; ++g) {
        const ush* bw = Whp + ((size_t)(g * 128 + jcol)) * 128 + lq * 8;
        #pragma unroll
        for (int kf = 0; kf < 4; ++kf) whf[g][kf] = *(const short8*)(bw + kf * 32);
    }
    short8 wyf[4];
    #pragma unroll
    for (int kf = 0; kf < 4; ++kf) {
        short8 fr;
        #pragma unroll
        for (int j = 0; j < 8; ++j)
            fr[j] = (l16 < 3) ? (short)f2bf(Wy[l16 * 128 + kf * 32 + lq * 8 + j]) : (short)0;
        wyf[kf] = fr;
    }
    const float byl = (l16 < 3) ? by[l16] : 0.f;

    // hoisted LDS offsets (invariant across steps)
    int oaf[4], ohw[4];
    #pragma unroll
    for (int kf = 0; kf < 4; ++kf)
        oaf[kf] = ((l16 * 128 + kf * 32 + lq * 8) * 2) ^ ((l16 & 7) << 4);
    #pragma unroll
    for (int q = 0; q < 4; ++q) {
        int rr = lq * 4 + q;
        ohw[q] = ((rr * 128 + jcol) * 2) ^ ((rr & 7) << 4);
    }
    // hoisted out0 pointers (bumped +128 per step)
    float* op[4];
    #pragma unroll
    for (int q = 0; q < 4; ++q)
        op[q] = out0 + (size_t)(b0 + lq * 4 + q) * (270 * 128) + (size_t)t0 * 128 + jcol;

    {   // zero both h buffers (h_0 = 0; rows 4-15 permanent zero padding)
        ush* hp = &h_lds[0][0];
        for (int idx = tid; idx < 2 * 16 * 128; idx += 512) hp[idx] = 0;
    }
    __syncthreads();

    float c[4] = {0.f, 0.f, 0.f, 0.f};
    if (t0 != 0) {
        #pragma unroll
        for (int q = 0; q < 4; ++q)
            c[q] = c_state[(size_t)(b0 + lq * 4 + q) * 128 + jcol];
        for (int idx = tid; idx < 2048; idx += 512) {
            int rr = idx >> 7, k = idx & 127;
            float hvv = out0[(size_t)(b0 + rr) * (270 * 128) + (size_t)(t0 - 1) * 128 + k];
            int off = ((rr * 128 + k) * 2) ^ ((rr & 7) << 4);
            *(ush*)(hbase + off) = f2bf(hvv);
        }
        __syncthreads();
    }

    const size_t TSTEP = (size_t)64 * 512 * 16;         // ush per timestep
    const ush* xb = xpc + (size_t)blockIdx.x * 8192;
    int go[4];
    #pragma unroll
    for (int g = 0; g < 4; ++g) go[g] = (g * 128 + jcol) * 16 + lq * 4;

    u32x2 Pa[4], Pb[4];
    #pragma unroll
    for (int g = 0; g < 4; ++g) Pa[g] = *(const u32x2*)(xb + go[g]);
    #pragma unroll
    for (int g = 0; g < 4; ++g) Pb[g] = *(const u32x2*)(xb + TSTEP + go[g]);
    const ush* xpa = xb + 2 * TSTEP;                    // prefetch src for Pa (t+2)
    const ush* xpb = xb + 3 * TSTEP;                    // prefetch src for Pb (t+3)

    for (int t = t0; t < t1; t += 2) {    // chunk lengths are even
        STEPB(t, Pa, xpa, 0)
        STEPB(t + 1, Pb, xpb, 1)
    }

    // epilogue: logits/softmax for the last h (t1-1), now in h_lds[0]
    {
        short8 afr[4];
        #pragma unroll
        for (int kf = 0; kf < 4; ++kf)
            afr[kf] = *(const short8*)(hbase + oaf[kf]);
        if (w < 4) {
            f32x4 ay = (f32x4){0.f, 0.f, 0.f, 0.f};
            ay = __builtin_amdgcn_mfma_f32_16x16x32_bf16(afr[0], wyf[0], ay, 0, 0, 0);
            ay = __builtin_amdgcn_mfma_f32_16x16x32_bf16(afr[1], wyf[1], ay, 0, 0, 0);
            ay = __builtin_amdgcn_mfma_f32_16x16x32_bf16(afr[2], wyf[2], ay, 0, 0, 0);
            ay = __builtin_amdgcn_mfma_f32_16x16x32_bf16(afr[3], wyf[3], ay, 0, 0, 0);
            float L = ((w == 0) ? ay[0] : (w == 1) ? ay[1] : (w == 2) ? ay[2] : ay[3]) + byl;
            if (l16 >= 3) L = -1e30f;
            float m = fmaxf(L, __shfl_xor(L, 1));
            m = fmaxf(m, __shfl_xor(m, 2));
            float e = (l16 < 3) ? __expf(L - m) : 0.f;
            float s = e + __shfl_xor(e, 1);
            s = s + __shfl_xor(s, 2);
            if (l16 < 3)
                out1[((size_t)(b0 + lq * 4 + w) * 270 + (t1 - 1)) * 3 + l16] =
                    e * __builtin_amdgcn_rcpf(s);
        }
    }

    if (t1 != 270) {
        #pragma unroll
        for (int q = 0; q < 4; ++q)
            c_state[(size_t)(b0 + lq * 4 + q) * 128 + jcol] = c[q];
    }
}

// ---------------- host ----------------
extern "C" void kernel_launch(void* const* d_in, const int* in_sizes, int n_in,
                              void* d_out, int out_size, void* d_ws, size_t ws_size,
                              hipStream_t stream) {
    (void)in_sizes; (void)n_in; (void)out_size;
    const float* x   = (const float*)d_in[0];
    const float* Wf  = (const float*)d_in[1];
    const float* Wi  = (const float*)d_in[2];
    const float* Wc  = (const float*)d_in[3];
    const float* Wo  = (const float*)d_in[4];
    const float* Wy  = (const float*)d_in[5];
    const float* bfp = (const float*)d_in[6];
    const float* bip = (const float*)d_in[7];
    const float* bcp = (const float*)d_in[8];
    const float* bop = (const float*)d_in[9];
    const float* byp = (const float*)d_in[10];

    float* out0 = (float*)d_out;                       // [B,T,H]
    float* out1 = out0 + (size_t)1024 * 270 * 128;     // [B,T,3]

    long tc = 6;
    {
        const long cand[6] = {270, 90, 54, 30, 18, 6};
        for (int i = 0; i < 6; ++i) {
            size_t need = (size_t)cand[i] * 1048576u + (2u << 20);
            if (need <= ws_size) { tc = cand[i]; break; }
        }
    }
    char* wsb = (char*)d_ws;
    ush* xpc = (ush*)wsb;                              // tc MB
    char* fx = wsb + (size_t)tc * 1048576u;
    float* c_state = (float*)fx;                       // 512 KB
    ush* Wxp = (ush*)(fx + 524288);                    // 288 KB
    ush* Whp = (ush*)(fx + 524288 + 294912);           // 128 KB
    float* bpk = (float*)(fx + 524288 + 294912 + 131072);

    pack_w<<<576, 256, 0, stream>>>(Wf, Wi, Wc, Wo, bfp, bip, bcp, bop, Wxp, Whp, bpk);

    for (int t0 = 0; t0 < 270; t0 += (int)tc) {
        int Tcur = (270 - t0) < (int)tc ? (270 - t0) : (int)tc;
        int rows = Tcur * 1024;
        xp_gemm<<<rows / 64, 256, 0, stream>>>(x, Wxp, bpk, xpc, t0);
        lstm_scan<<<64, 512, 0, stream>>>(xpc, Whp, c_state, out0, out1, Wy, byp,
                                          t0, t0 + Tcur);
    }
}

// Round 18
// 450.800 us; speedup vs baseline: 1.2838x; 1.0525x over previous
//
#include <hip/hip_runtime.h>
#include <stdint.h>

// LSTM forward, MI355X. H=128, I=270, C=3, B=1024, T=270, NU=512, W rows 398.
// Round-18: r17 with the compile fix — __exp2f (not a HIP device fn, collided
// with glibc math.h) -> __builtin_amdgcn_exp2f (clang builtin, v_exp_f32,
// compiler-visible so TRANS hazards are handled; r16's inline-asm NaN avoided).
//   - pack_w scales Wx/Wh/bias by log2(e); gate exps in exp2 domain
//   - clamps via __builtin_amdgcn_fmed3f
//   - h-store proven f2bf; xp_gemm store proven scalar path

typedef __attribute__((ext_vector_type(8))) short short8;
typedef __attribute__((ext_vector_type(4))) float f32x4;
typedef __attribute__((ext_vector_type(2))) float f32x2;
typedef __attribute__((ext_vector_type(4))) unsigned int uint4v;
typedef __attribute__((ext_vector_type(2))) unsigned int u32x2;
typedef unsigned short ush;

#define LOG2E 1.4426950408889634f
#define TWOLOG2E 2.8853900817779268f

__device__ __forceinline__ ush f2bf(float f) {
    unsigned u = __float_as_uint(f);
    return (ush)((u + 0x7FFFu + ((u >> 16) & 1u)) >> 16);
}
// Raw barrier: LDS visibility only; vmem ops stay outstanding (T4).
__device__ __forceinline__ void lds_barrier() {
    asm volatile("s_waitcnt lgkmcnt(0)" ::: "memory");
    __builtin_amdgcn_s_barrier();
    __builtin_amdgcn_sched_barrier(0);
    asm volatile("" ::: "memory");
}

// ---------------- pack_w (weights pre-scaled by log2e) ----------------
__global__ __launch_bounds__(256) void pack_w(
    const float* __restrict__ Wf, const float* __restrict__ Wi,
    const float* __restrict__ Wc, const float* __restrict__ Wo,
    const float* __restrict__ bf_, const float* __restrict__ bi_,
    const float* __restrict__ bc_, const float* __restrict__ bo_,
    ush* __restrict__ Wxp, ush* __restrict__ Whp, float* __restrict__ bpk)
{
    int idx = blockIdx.x * 256 + threadIdx.x;
    if (idx < 512 * 288) {
        int u = idx / 288, i = idx - u * 288;
        int g = u >> 7, j = u & 127;
        const float* Wg = (g == 0) ? Wf : (g == 1) ? Wi : (g == 2) ? Wc : Wo;
        float v = (i < 270) ? Wg[(size_t)j * 398 + 128 + i] * LOG2E : 0.f;
        Wxp[idx] = f2bf(v);
    }
    if (idx < 512 * 128) {
        int u = idx >> 7, k = idx & 127;
        int g = u >> 7, j = u & 127;
        const float* Wg = (g == 0) ? Wf : (g == 1) ? Wi : (g == 2) ? Wc : Wo;
        Whp[idx] = f2bf(Wg[(size_t)j * 398 + k] * LOG2E);
    }
    if (idx < 512) {
        int g = idx >> 7, j = idx & 127;
        const float* bg = (g == 0) ? bf_ : (g == 1) ? bi_ : (g == 2) ? bc_ : bo_;
        bpk[idx] = bg[j] * LOG2E;
    }
}

// ---------------- xp_gemm: x read once; xpc layout [t][b/16][512u][16b] ----------------
__global__ __launch_bounds__(256, 2) void xp_gemm(
    const float* __restrict__ x, const ush* __restrict__ Wxp,
    const float* __restrict__ bpk, ush* __restrict__ xpc, int t0)
{
    __shared__ ush A_lds[64 * 296];                 // stride 296 elem -> 2-way banks
    const int tid = threadIdx.x;
    const int l = tid & 63, w = tid >> 6;
    const int l16 = l & 15, lq = l >> 4;
    const size_t row0 = (size_t)blockIdx.x * 64;

    // ---- issue all A loads (fp32) ----
    const int srow = tid >> 2, sgrp = tid & 3;      // row 0..63, 8-col group 0..3
    const int r = (int)row0 + srow;
    const int b = r & 1023, tt = (r >> 10) + t0;
    const float* xrow = x + ((size_t)b * 270 + tt) * 270;
    f32x2 stg[9][4];
    #pragma unroll
    for (int ks = 0; ks < 9; ++ks) {
        const int col = ks * 32 + sgrp * 8;
        const float* p = xrow + col;
        if (col + 8 <= 270) {
            stg[ks][0] = *(const f32x2*)p;       stg[ks][1] = *(const f32x2*)(p + 2);
            stg[ks][2] = *(const f32x2*)(p + 4); stg[ks][3] = *(const f32x2*)(p + 6);
        } else {
            float tv[8];
            #pragma unroll
            for (int j = 0; j < 8; ++j) tv[j] = (col + j < 270) ? p[j] : 0.f;
            stg[ks][0] = (f32x2){tv[0], tv[1]}; stg[ks][1] = (f32x2){tv[2], tv[3]};
            stg[ks][2] = (f32x2){tv[4], tv[5]}; stg[ks][3] = (f32x2){tv[6], tv[7]};
        }
    }

    // ---- B-frag base + prefetch ks=0 set; bias ----
    const ush* bptr = Wxp + ((size_t)(w * 128 + l16)) * 288 + lq * 8;
    short8 bA[8], bB[8];
    #pragma unroll
    for (int nt = 0; nt < 8; ++nt) bA[nt] = *(const short8*)(bptr + nt * 4608);
    float bias_v[8];
    #pragma unroll
    for (int nt = 0; nt < 8; ++nt) bias_v[nt] = bpk[w * 128 + nt * 16 + l16];

    // ---- convert + LDS write, one barrier ----
    {
        ush* wrow = &A_lds[srow * 296 + sgrp * 8];
        #pragma unroll
        for (int ks = 0; ks < 9; ++ks) {
            uint4v o;
            #pragma unroll
            for (int p2 = 0; p2 < 4; ++p2) {
                unsigned v;
                asm("v_cvt_pk_bf16_f32 %0, %1, %2"
                    : "=v"(v) : "v"(stg[ks][p2].x), "v"(stg[ks][p2].y));
                o[p2] = v;
            }
            *(uint4v*)(wrow + ks * 32) = o;
        }
    }
    lds_barrier();                                  // bA loads stay in flight

    f32x4 acc[4][8];
    #pragma unroll
    for (int mt = 0; mt < 4; ++mt)
        #pragma unroll
        for (int nt = 0; nt < 8; ++nt)
            acc[mt][nt] = (f32x4){bias_v[nt], bias_v[nt], bias_v[nt], bias_v[nt]};

    // ---- barrier-free K-loop ----
    #pragma unroll
    for (int ks = 0; ks < 9; ++ks) {
        short8* cur = (ks & 1) ? bB : bA;
        short8* nxt = (ks & 1) ? bA : bB;
        if (ks + 1 < 9) {
            const ush* np = bptr + (ks + 1) * 32;
            #pragma unroll
            for (int nt = 0; nt < 8; ++nt) nxt[nt] = *(const short8*)(np + nt * 4608);
        }
        short8 afr[4];
        #pragma unroll
        for (int mt = 0; mt < 4; ++mt)
            afr[mt] = *(const short8*)(&A_lds[(mt * 16 + l16) * 296 + ks * 32 + lq * 8]);
        #pragma unroll
        for (int mt = 0; mt < 4; ++mt)
            #pragma unroll
            for (int nt = 0; nt < 8; ++nt)
                acc[mt][nt] = __builtin_amdgcn_mfma_f32_16x16x32_bf16(
                    afr[mt], cur[nt], acc[mt][nt], 0, 0, 0);
    }

    // ---- store: [t][b/16][512u][16b], proven f2bf scalar path ----
    const int tloc = (int)(row0 >> 10);
    const int bg0 = ((int)row0 & 1023) >> 4;
    #pragma unroll
    for (int mt = 0; mt < 4; ++mt)
        #pragma unroll
        for (int nt = 0; nt < 8; ++nt) {
            int u = w * 128 + nt * 16 + l16;
            ush* dst = xpc + ((size_t)(tloc * 64 + bg0 + mt) * 512 + u) * 16 + lq * 4;
            #pragma unroll
            for (int q = 0; q < 4; ++q) dst[q] = f2bf(acc[mt][nt][q]);
        }
}

// ---------------- lstm_scan: 16 rows/block, exp2-domain gates ----------------
// Pre-acts arrive scaled by log2e; exps via __builtin_amdgcn_exp2f (hazard-safe).
#define STEPB(T, PS, XP, CUR)                                                   \
  {                                                                             \
    const int t_ = (T);                                                         \
    const bool lw_ = (((w >> 2) ^ (t_ & 1)) == 0) && (t_ > t0);                 \
    short8 afr[4];                                                              \
    _Pragma("unroll") for (int kf = 0; kf < 4; ++kf)                            \
      afr[kf] = *(const short8*)(hbase + (CUR) * 4096 + oaf[kf]);               \
    f32x4 acc_[4];                                                              \
    _Pragma("unroll") for (int g = 0; g < 4; ++g) {                             \
      u32x2 pv_ = PS[g];                                                        \
      acc_[g][0] = __uint_as_float(pv_.x << 16);                                \
      acc_[g][1] = __uint_as_float(pv_.x & 0xffff0000u);                        \
      acc_[g][2] = __uint_as_float(pv_.y << 16);                                \
      acc_[g][3] = __uint_as_float(pv_.y & 0xffff0000u);                        \
    }                                                                           \
    if (t_ + 2 < t1) {                                                          \
      _Pragma("unroll") for (int g = 0; g < 4; ++g)                             \
        PS[g] = *(const u32x2*)((XP) + go[g]);                                  \
    }                                                                           \
    (XP) += 2 * TSTEP;                                                          \
    _Pragma("unroll") for (int kf = 0; kf < 4; ++kf)                            \
      _Pragma("unroll") for (int g = 0; g < 4; ++g)                             \
        acc_[g] = __builtin_amdgcn_mfma_f32_16x16x32_bf16(                      \
            afr[kf], whf[g][kf], acc_[g], 0, 0, 0);                             \
    f32x4 ay_ = (f32x4){0.f, 0.f, 0.f, 0.f};                                    \
    if (lw_) {                /* logits for t_-1 (afr = h_{t_-1}) */            \
      ay_ = __builtin_amdgcn_mfma_f32_16x16x32_bf16(afr[0], wyf[0], ay_, 0, 0, 0); \
      ay_ = __builtin_amdgcn_mfma_f32_16x16x32_bf16(afr[1], wyf[1], ay_, 0, 0, 0); \
      ay_ = __builtin_amdgcn_mfma_f32_16x16x32_bf16(afr[2], wyf[2], ay_, 0, 0, 0); \
      ay_ = __builtin_amdgcn_mfma_f32_16x16x32_bf16(afr[3], wyf[3], ay_, 0, 0, 0); \
    }                                                                           \
    _Pragma("unroll") for (int q = 0; q < 4; ++q) {                             \
      float pf_ = __builtin_amdgcn_fmed3f(acc_[0][q], -28.f, 28.f);             \
      float pi_ = __builtin_amdgcn_fmed3f(acc_[1][q], -28.f, 28.f);             \
      float pc2_ = __builtin_amdgcn_fmed3f(acc_[2][q] + acc_[2][q], -28.f, 28.f); \
      float po_ = __builtin_amdgcn_fmed3f(acc_[3][q], -28.f, 28.f);             \
      float ef_ = __builtin_amdgcn_exp2f(-pf_);                                 \
      float ei_ = __builtin_amdgcn_exp2f(-pi_);                                 \
      float ec2_ = __builtin_amdgcn_exp2f(-pc2_);                               \
      float eo_ = __builtin_amdgcn_exp2f(-po_);                                 \
      float df_ = 1.f + ef_;                                                    \
      float di_ = 1.f + ei_;                                                    \
      float dc_ = 1.f + ec2_;                                                   \
      float do2_ = 1.f + eo_;                                                   \
      float didc_ = di_ * dc_;                                                  \
      float num_ = c[q] * didc_ + (1.f - ec2_) * df_;                           \
      float cn_ = num_ * __builtin_amdgcn_rcpf(df_ * didc_);                    \
      c[q] = cn_;                                                               \
      float t2_ = __builtin_amdgcn_fmed3f(cn_, -10.f, 10.f);                    \
      float et2_ = __builtin_amdgcn_exp2f(-TWOLOG2E * t2_);                     \
      float hv_ = (1.f - et2_) * __builtin_amdgcn_rcpf(do2_ * (1.f + et2_));    \
      *(ush*)(hbase + ((CUR) ^ 1) * 4096 + ohw[q]) = f2bf(hv_);                 \
      *op[q] = hv_;                                                             \
      op[q] += 128;                                                             \
    }                                                                           \
    lds_barrier();                                                              \
    /* softmax finish AFTER the barrier: overlaps next step's ds_read+MFMA */   \
    if (lw_) {                                                                  \
      int ww_ = w & 3;                                                          \
      float L_ = ((ww_ == 0) ? ay_[0] : (ww_ == 1) ? ay_[1] : (ww_ == 2) ? ay_[2] : ay_[3]) + byl; \
      if (l16 >= 3) L_ = -1e30f;                                                \
      float m_ = fmaxf(L_, __shfl_xor(L_, 1));                                  \
      m_ = fmaxf(m_, __shfl_xor(m_, 2));                                        \
      float e_ = (l16 < 3) ? __expf(L_ - m_) : 0.f;                             \
      float s_ = e_ + __shfl_xor(e_, 1);                                        \
      s_ = s_ + __shfl_xor(s_, 2);                                              \
      if (l16 < 3)                                                              \
        out1[((size_t)(b0 + lq * 4 + ww_) * 270 + (t_ - 1)) * 3 + l16] = e_ * __builtin_amdgcn_rcpf(s_); \
    }                                                                           \
  }

__global__ __launch_bounds__(512) void lstm_scan(
    const ush* __restrict__ xpc, const ush* __restrict__ Whp,
    float* __restrict__ c_state, float* __restrict__ out0, float* __restrict__ out1,
    const float* __restrict__ Wy, const float* __restrict__ by, int t0, int t1)
{
    __shared__ ush h_lds[2][16 * 128];
    const int tid = threadIdx.x;
    const int l = tid & 63, w = tid >> 6;
    const int l16 = l & 15, lq = l >> 4;
    const int b0 = blockIdx.x * 16;
    const int jcol = w * 16 + l16;
    char* hbase = (char*)&h_lds[0][0];

    short8 whf[4][4];
    #pragma unroll
    for (int g = 0; g < 4; ++g) {
        const ush* bw = Whp + ((size_t)(g * 128 + jcol)) * 128 + lq * 8;
        #pragma unroll
        for (int kf = 0; kf < 4; ++kf) whf[g][kf] = *(const short8*)(bw + kf * 32);
    }
    short8 wyf[4];
    #pragma unroll
    for (int kf = 0; kf < 4; ++kf) {
        short8 fr;
        #pragma unroll
        for (int j = 0; j < 8; ++j)
            fr[j] = (l16 < 3) ? (short)f2bf(Wy[l16 * 128 + kf * 32 + lq * 8 + j]) : (short)0;
        wyf[kf] = fr;
    }
    const float byl = (l16 < 3) ? by[l16] : 0.f;

    // hoisted LDS offsets (invariant across steps)
    int oaf[4], ohw[4];
    #pragma unroll
    for (int kf = 0; kf < 4; ++kf)
        oaf[kf] = ((l16 * 128 + kf * 32 + lq * 8) * 2) ^ ((l16 & 7) << 4);
    #pragma unroll
    for (int q = 0; q < 4; ++q) {
        int rr = lq * 4 + q;
        ohw[q] = ((rr * 128 + jcol) * 2) ^ ((rr & 7) << 4);
    }
    // hoisted out0 pointers (bumped +128 per step)
    float* op[4];
    #pragma unroll
    for (int q = 0; q < 4; ++q)
        op[q] = out0 + (size_t)(b0 + lq * 4 + q) * (270 * 128) + (size_t)t0 * 128 + jcol;

    {   // zero both h buffers (h_0 = 0; rows 4-15 permanent zero padding)
        ush* hp = &h_lds[0][0];
        for (int idx = tid; idx < 2 * 16 * 128; idx += 512) hp[idx] = 0;
    }
    __syncthreads();

    float c[4] = {0.f, 0.f, 0.f, 0.f};
    if (t0 != 0) {
        #pragma unroll
        for (int q = 0; q < 4; ++q)
            c[q] = c_state[(size_t)(b0 + lq * 4 + q) * 128 + jcol];
        for (int idx = tid; idx < 2048; idx += 512) {
            int rr = idx >> 7, k = idx & 127;
            float hvv = out0[(size_t)(b0 + rr) * (270 * 128) + (size_t)(t0 - 1) * 128 + k];
            int off = ((rr * 128 + k) * 2) ^ ((rr & 7) << 4);
            *(ush*)(hbase + off) = f2bf(hvv);
        }
        __syncthreads();
    }

    const size_t TSTEP = (size_t)64 * 512 * 16;         // ush per timestep
    const ush* xb = xpc + (size_t)blockIdx.x * 8192;
    int go[4];
    #pragma unroll
    for (int g = 0; g < 4; ++g) go[g] = (g * 128 + jcol) * 16 + lq * 4;

    u32x2 Pa[4], Pb[4];
    #pragma unroll
    for (int g = 0; g < 4; ++g) Pa[g] = *(const u32x2*)(xb + go[g]);
    #pragma unroll
    for (int g = 0; g < 4; ++g) Pb[g] = *(const u32x2*)(xb + TSTEP + go[g]);
    const ush* xpa = xb + 2 * TSTEP;                    // prefetch src for Pa (t+2)
    const ush* xpb = xb + 3 * TSTEP;                    // prefetch src for Pb (t+3)

    for (int t = t0; t < t1; t += 2) {    // chunk lengths are even
        STEPB(t, Pa, xpa, 0)
        STEPB(t + 1, Pb, xpb, 1)
    }

    // epilogue: logits/softmax for the last h (t1-1), now in h_lds[0]
    {
        short8 afr[4];
        #pragma unroll
        for (int kf = 0; kf < 4; ++kf)
            afr[kf] = *(const short8*)(hbase + oaf[kf]);
        if (w < 4) {
            f32x4 ay = (f32x4){0.f, 0.f, 0.f, 0.f};
            ay = __builtin_amdgcn_mfma_f32_16x16x32_bf16(afr[0], wyf[0], ay, 0, 0, 0);
            ay = __builtin_amdgcn_mfma_f32_16x16x32_bf16(afr[1], wyf[1], ay, 0, 0, 0);
            ay = __builtin_amdgcn_mfma_f32_16x16x32_bf16(afr[2], wyf[2], ay, 0, 0, 0);
            ay = __builtin_amdgcn_mfma_f32_16x16x32_bf16(afr[3], wyf[3], ay, 0, 0, 0);
            float L = ((w == 0) ? ay[0] : (w == 1) ? ay[1] : (w == 2) ? ay[2] : ay[3]) + byl;
            if (l16 >= 3) L = -1e30f;
            float m = fmaxf(L, __shfl_xor(L, 1));
            m = fmaxf(m, __shfl_xor(m, 2));
            float e = (l16 < 3) ? __expf(L - m) : 0.f;
            float s = e + __shfl_xor(e, 1);
            s = s + __shfl_xor(s, 2);
            if (l16 < 3)
                out1[((size_t)(b0 + lq * 4 + w) * 270 + (t1 - 1)) * 3 + l16] =
                    e * __builtin_amdgcn_rcpf(s);
        }
    }

    if (t1 != 270) {
        #pragma unroll
        for (int q = 0; q < 4; ++q)
            c_state[(size_t)(b0 + lq * 4 + q) * 128 + jcol] = c[q];
    }
}

// ---------------- host ----------------
extern "C" void kernel_launch(void* const* d_in, const int* in_sizes, int n_in,
                              void* d_out, int out_size, void* d_ws, size_t ws_size,
                              hipStream_t stream) {
    (void)in_sizes; (void)n_in; (void)out_size;
    const float* x   = (const float*)d_in[0];
    const float* Wf  = (const float*)d_in[1];
    const float* Wi  = (const float*)d_in[2];
    const float* Wc  = (const float*)d_in[3];
    const float* Wo  = (const float*)d_in[4];
    const float* Wy  = (const float*)d_in[5];
    const float* bfp = (const float*)d_in[6];
    const float* bip = (const float*)d_in[7];
    const float* bcp = (const float*)d_in[8];
    const float* bop = (const float*)d_in[9];
    const float* byp = (const float*)d_in[10];

    float* out0 = (float*)d_out;                       // [B,T,H]
    float* out1 = out0 + (size_t)1024 * 270 * 128;     // [B,T,3]

    long tc = 6;
    {
        const long cand[6] = {270, 90, 54, 30, 18, 6};
        for (int i = 0; i < 6; ++i) {
            size_t need = (size_t)cand[i] * 1048576u + (2u << 20);
            if (need <= ws_size) { tc = cand[i]; break; }
        }
    }
    char* wsb = (char*)d_ws;
    ush* xpc = (ush*)wsb;                              // tc MB
    char* fx = wsb + (size_t)tc * 1048576u;
    float* c_state = (float*)fx;                       // 512 KB
    ush* Wxp = (ush*)(fx + 524288);                    // 288 KB
    ush* Whp = (ush*)(fx + 524288 + 294912);           // 128 KB
    float* bpk = (float*)(fx + 524288 + 294912 + 131072);

    pack_w<<<576, 256, 0, stream>>>(Wf, Wi, Wc, Wo, bfp, bip, bcp, bop, Wxp, Whp, bpk);

    for (int t0 = 0; t0 < 270; t0 += (int)tc) {
        int Tcur = (270 - t0) < (int)tc ? (270 - t0) : (int)tc;
        int rows = Tcur * 1024;
        xp_gemm<<<rows / 64, 256, 0, stream>>>(x, Wxp, bpk, xpc, t0);
        lstm_scan<<<64, 512, 0, stream>>>(xpc, Whp, c_state, out0, out1, Wy, byp,
                                          t0, t0 + Tcur);
    }
}